// Round 6
// baseline (175.765 us; speedup 1.0000x reference)
//
#include <hip/hip_runtime.h>
#include <stdint.h>
#include <stddef.h>

// ---------------- types ----------------
typedef __attribute__((ext_vector_type(8))) short bf16x8;          // MFMA A/B frag (8 bf16)
typedef __attribute__((ext_vector_type(4))) short bf16x4;          // 8B half-frag
typedef __attribute__((ext_vector_type(4))) float f32x4;           // MFMA C/D frag

__device__ __forceinline__ uint16_t f2bf(float f) {
  uint32_t u = __builtin_bit_cast(uint32_t, f);
  u += 0x7fffu + ((u >> 16) & 1u);   // RNE
  return (uint16_t)(u >> 16);
}

// ---------------- problem constants ----------------
#define MB   16384      // batch
#define NP   256        // W*H positions
#define KDIM 1024       // NP*EMB
#define NDIM 1024       // OUT
#define NCLS 1024       // embedding classes

#define NH  32          // half-steps: 32 k each

// ================= fragment-major Btf layout (unchanged, verified) ========
// Per (bn, s) chunk of 8192 uint16: unit u = g*64 + q*16 + m (16B each),
//   g = (col>>4)&15, m = col&15, q = k-quad. A wave's B-frag j at lane l
//   is unit ((wc*4+j)*64 + l) -> consecutive 16B per lane, perfectly
//   coalesced whether read by LDS-DMA or (now) directly into VGPRs.

// ---------------- kernel 1: Btf = frag-major bf16(W_dense^T) ----------------
__global__ void build_bt_kernel(const float* __restrict__ Wd,
                                uint16_t* __restrict__ Btf) {
  __shared__ uint16_t tile[32][33];               // +1 pad: no bank conflicts
  const int k0 = blockIdx.y * 32;
  const int n0 = blockIdx.x * 32;
  const int tx = threadIdx.x;                     // 0..31
  const int ty = threadIdx.y;                     // 0..7
  #pragma unroll
  for (int r = 0; r < 32; r += 8)
    tile[ty + r][tx] = f2bf(Wd[(size_t)(k0 + ty + r) * NDIM + n0 + tx]);
  __syncthreads();
  #pragma unroll
  for (int r = 0; r < 32; r += 8) {
    const int n = n0 + ty + r;                    // output col
    const int k = k0 + tx;                        // reduction index
    const int bn = n >> 8, g = (n >> 4) & 15, m = n & 15;
    const int s = k >> 5, q = (k >> 3) & 3, e = k & 7;   // half-step, k-quad, elem
    Btf[(size_t)(bn * NH + s) * 8192 + (size_t)(g * 64 + q * 16 + m) * 8 + e]
        = tile[tx][ty + r];
  }
}

// ---------------- kernel 2: fused embed-gather + bf16 GEMM, barrier-free ----
// 256 threads = 4 waves, wave grid 1(M)x4(N): 64 rows x 256 cols per block.
// Grid 256 x 4. LDS holds ONLY the 8-KB embed table; B-frags stream directly
// from the L2-resident frag-major Btf into registers (prefetched 1 half-step
// ahead); A-frags are gathered per-lane from the table. NO in-loop barriers:
// waves run free, latency hidden by wave multiplicity.
__global__ __launch_bounds__(256) void fused_gemm_kernel(
    const int* __restrict__ x,
    const float* __restrict__ We,
    const float* __restrict__ be,
    const uint16_t* __restrict__ Btf,
    const float* __restrict__ bias,
    float* __restrict__ C) {
  __shared__ __align__(16) uint16_t web[NCLS * 4];   // 8 KB: bf16(We[c][e]+be[e])

  const int tid = threadIdx.x;
  const int bm  = blockIdx.x;            // 0..255 (64-row band)
  const int bn  = blockIdx.y;            // 0..3   (256-col band)
  const int w   = tid >> 6;              // wave = wc, 0..3 (64-col sub-band)
  const int l   = tid & 63;
  const int lm  = l & 15;
  const int q4  = l >> 4;

  const int row0 = bm * 64;
  const int col0 = bn * 256;

  // ---- embed table -> LDS (bias folded, bf16) ----
  {
    const float4 bb = *(const float4*)be;
    #pragma unroll
    for (int c0 = 0; c0 < NCLS; c0 += 256) {
      const int c = c0 + tid;
      const float4 wv = *(const float4*)(We + (size_t)c * 4);
      bf16x4 t;
      t[0] = (short)f2bf(wv.x + bb.x);
      t[1] = (short)f2bf(wv.y + bb.y);
      t[2] = (short)f2bf(wv.z + bb.z);
      t[3] = (short)f2bf(wv.w + bb.w);
      *(bf16x4*)(web + (size_t)c * 4) = t;
    }
  }
  __syncthreads();                       // table visible; the ONLY block barrier

  // ---- per-lane source pointers ----
  // A: lane needs class pairs for rows row0 + i*16 + lm, positions q4*2 + s*8.
  const int* xr0 = x + (size_t)(row0 +  0 + lm) * NP + q4 * 2;
  const int* xr1 = x + (size_t)(row0 + 16 + lm) * NP + q4 * 2;
  const int* xr2 = x + (size_t)(row0 + 32 + lm) * NP + q4 * 2;
  const int* xr3 = x + (size_t)(row0 + 48 + lm) * NP + q4 * 2;
  // B: lane reads unit ((w*4+j)*64 + l) of chunk (bn*NH + s).
  const uint16_t* bp = Btf + (size_t)bn * (NH * 8192) + (size_t)((w * 4) * 64 + l) * 8;

  f32x4 acc[4][4];
  #pragma unroll
  for (int i = 0; i < 4; i++)
    #pragma unroll
    for (int j = 0; j < 4; j++)
      acc[i][j] = (f32x4){0.f, 0.f, 0.f, 0.f};

  // ---- prologue: s=0 operands ----
  int2 xq[4], xn[4];
  bf16x8 bcur[4], bnxt[4];
  xq[0] = *(const int2*)xr0;
  xq[1] = *(const int2*)xr1;
  xq[2] = *(const int2*)xr2;
  xq[3] = *(const int2*)xr3;
  #pragma unroll
  for (int j = 0; j < 4; j++)
    bcur[j] = *(const bf16x8*)(bp + (size_t)j * 512);

  // ---- main loop: no barriers, depth-1 register prefetch ----
  for (int s = 0; s < NH - 1; ++s) {
    // prefetch s+1 (vmem, register-destined; slack = one full iteration)
    const uint16_t* bq = bp + (size_t)(s + 1) * 8192;
    #pragma unroll
    for (int j = 0; j < 4; j++)
      bnxt[j] = *(const bf16x8*)(bq + (size_t)j * 512);
    xn[0] = *(const int2*)(xr0 + (s + 1) * 8);
    xn[1] = *(const int2*)(xr1 + (s + 1) * 8);
    xn[2] = *(const int2*)(xr2 + (s + 1) * 8);
    xn[3] = *(const int2*)(xr3 + (s + 1) * 8);

    // A-frags: 8 ds_read_b64 gathers from the table
    bf16x8 af[4];
    #pragma unroll
    for (int i = 0; i < 4; i++) {
      union { bf16x8 v; struct { bf16x4 lo, hi; } s_; } u;
      u.s_.lo = *(const bf16x4*)(web + ((unsigned)xq[i].x * 4u));
      u.s_.hi = *(const bf16x4*)(web + ((unsigned)xq[i].y * 4u));
      af[i] = u.v;
    }

    __builtin_amdgcn_s_setprio(1);
    #pragma unroll
    for (int i = 0; i < 4; i++)
      #pragma unroll
      for (int j = 0; j < 4; j++)
        acc[i][j] = __builtin_amdgcn_mfma_f32_16x16x32_bf16(af[i], bcur[j], acc[i][j], 0, 0, 0);
    __builtin_amdgcn_s_setprio(0);

    #pragma unroll
    for (int j = 0; j < 4; j++) bcur[j] = bnxt[j];
    #pragma unroll
    for (int i = 0; i < 4; i++) xq[i] = xn[i];
  }

  // ---- peeled s = NH-1 ----
  {
    bf16x8 af[4];
    #pragma unroll
    for (int i = 0; i < 4; i++) {
      union { bf16x8 v; struct { bf16x4 lo, hi; } s_; } u;
      u.s_.lo = *(const bf16x4*)(web + ((unsigned)xq[i].x * 4u));
      u.s_.hi = *(const bf16x4*)(web + ((unsigned)xq[i].y * 4u));
      af[i] = u.v;
    }
    __builtin_amdgcn_s_setprio(1);
    #pragma unroll
    for (int i = 0; i < 4; i++)
      #pragma unroll
      for (int j = 0; j < 4; j++)
        acc[i][j] = __builtin_amdgcn_mfma_f32_16x16x32_bf16(af[i], bcur[j], acc[i][j], 0, 0, 0);
    __builtin_amdgcn_s_setprio(0);
  }

  // ---- epilogue: D[row = q4*4 + r][col = lm] per 16x16 frag (m89/m91-verified) ----
  float bvals[4];
  #pragma unroll
  for (int j = 0; j < 4; j++)
    bvals[j] = bias[col0 + w * 64 + j * 16 + lm];

  #pragma unroll
  for (int i = 0; i < 4; i++) {
    const int rbase = row0 + i * 16 + q4 * 4;
    #pragma unroll
    for (int j = 0; j < 4; j++) {
      const int col = col0 + w * 64 + j * 16 + lm;
      #pragma unroll
      for (int r = 0; r < 4; r++)
        C[(size_t)(rbase + r) * NDIM + col] = acc[i][j][r] + bvals[j];
    }
  }
}

// ---------------- fallback (workspace too small): fp32 naive ----------------
__global__ void naive_kernel(const int* __restrict__ x,
                             const float* __restrict__ We,
                             const float* __restrict__ be,
                             const float* __restrict__ Wd,
                             const float* __restrict__ bd,
                             float* __restrict__ out) {
  __shared__ float emb[KDIM];
  const int b = blockIdx.x;
  const int tid = threadIdx.x;
  {
    const int cls = x[(size_t)b * NP + tid];
    const float4 e  = *(const float4*)(We + (size_t)cls * 4);
    const float4 bb = *(const float4*)be;
    emb[tid * 4 + 0] = e.x + bb.x;
    emb[tid * 4 + 1] = e.y + bb.y;
    emb[tid * 4 + 2] = e.z + bb.z;
    emb[tid * 4 + 3] = e.w + bb.w;
  }
  __syncthreads();
  float acc0 = bd[tid], acc1 = bd[tid + 256], acc2 = bd[tid + 512], acc3 = bd[tid + 768];
  for (int k = 0; k < KDIM; ++k) {
    const float a = emb[k];
    const float* wv = Wd + (size_t)k * NDIM + tid;
    acc0 += a * wv[0];
    acc1 += a * wv[256];
    acc2 += a * wv[512];
    acc3 += a * wv[768];
  }
  float* o = out + (size_t)b * NDIM + tid;
  o[0] = acc0; o[256] = acc1; o[512] = acc2; o[768] = acc3;
}

// ---------------- launch ----------------
extern "C" void kernel_launch(void* const* d_in, const int* in_sizes, int n_in,
                              void* d_out, int out_size, void* d_ws, size_t ws_size,
                              hipStream_t stream) {
  const int*   x  = (const int*)d_in[0];
  const float* We = (const float*)d_in[1];
  const float* be = (const float*)d_in[2];
  const float* Wd = (const float*)d_in[3];
  const float* bd = (const float*)d_in[4];
  float* out = (float*)d_out;

  const size_t needB = (size_t)NDIM * KDIM * sizeof(uint16_t);  // 2 MB

  if (ws_size >= needB) {
    uint16_t* Btw = (uint16_t*)d_ws;
    build_bt_kernel<<<dim3(NDIM / 32, KDIM / 32), dim3(32, 8), 0, stream>>>(Wd, Btw);
    fused_gemm_kernel<<<dim3(MB / 64, NDIM / 256), 256, 0, stream>>>(x, We, be, Btw, bd, out);
  } else {
    naive_kernel<<<MB, 256, 0, stream>>>(x, We, be, Wd, bd, out);
  }
}

// Round 8
// 136.112 us; speedup vs baseline: 1.2913x; 1.2913x over previous
//
#include <hip/hip_runtime.h>
#include <stdint.h>
#include <stddef.h>

// ---------------- types ----------------
typedef __attribute__((ext_vector_type(8))) short bf16x8;          // MFMA A/B frag (8 bf16)
typedef __attribute__((ext_vector_type(4))) short bf16x4;          // 8B half-frag
typedef __attribute__((ext_vector_type(4))) float f32x4;           // MFMA C/D frag

typedef const __attribute__((address_space(1))) void* gptr1_t;
typedef __attribute__((address_space(3))) void* lptr3_t;

#define GLOAD_LDS16(gp, lp) \
  __builtin_amdgcn_global_load_lds((gptr1_t)(gp), (lptr3_t)(lp), 16, 0, 0)

#define VMWAIT(N)  asm volatile("s_waitcnt vmcnt(" #N ")" ::: "memory")
#define MEMFENCE() asm volatile("" ::: "memory")

__device__ __forceinline__ uint16_t f2bf(float f) {
  uint32_t u = __builtin_bit_cast(uint32_t, f);
  u += 0x7fffu + ((u >> 16) & 1u);   // RNE
  return (uint16_t)(u >> 16);
}

// ---------------- problem constants ----------------
#define MB   16384      // batch
#define NP   256        // W*H positions
#define KDIM 1024       // NP*EMB
#define NDIM 1024       // OUT
#define NCLS 1024       // embedding classes

#define NH  32          // half-steps: 32 k each

// ================= fragment-major Btf layout (BN=512 chunks) =============
// Per (bn, s) chunk of 16384 uint16 (32 KB): unit u = g*64 + q*16 + m,
//   g = (col>>4)&31, m = col&15, q = k-quad. Wave w's B-frag j at lane l is
//   unit ((w*8+j)*64 + l) -> consecutive 16B per lane -> conflict-free LDS
//   reads AND linear coalesced global_load_lds staging (rule 21: both sides).

// ---------------- kernel 1: Btf = frag-major bf16(W_dense^T) ----------------
__global__ void build_bt_kernel(const float* __restrict__ Wd,
                                uint16_t* __restrict__ Btf) {
  __shared__ uint16_t tile[32][33];               // +1 pad: no bank conflicts
  const int k0 = blockIdx.y * 32;
  const int n0 = blockIdx.x * 32;
  const int tx = threadIdx.x;                     // 0..31
  const int ty = threadIdx.y;                     // 0..7
  #pragma unroll
  for (int r = 0; r < 32; r += 8)
    tile[ty + r][tx] = f2bf(Wd[(size_t)(k0 + ty + r) * NDIM + n0 + tx]);
  __syncthreads();
  #pragma unroll
  for (int r = 0; r < 32; r += 8) {
    const int n = n0 + ty + r;                    // output col
    const int k = k0 + tx;                        // reduction index
    const int bn = n >> 9, g = (n >> 4) & 31, m = n & 15;
    const int s = k >> 5, q = (k >> 3) & 3, e = k & 7;   // half-step, k-quad, elem
    Btf[(size_t)(bn * NH + s) * 16384 + (size_t)(g * 64 + q * 16 + m) * 8 + e]
        = tile[tx][ty + r];
  }
}

// ---------------- kernel 2: fused embed-gather + bf16 GEMM ----------------
// 256 threads = 4 waves, wave grid 1(M)x4(N): wave tile 64x128, block
// 64 rows x 512 cols, grid (256, 2). LDS: 8-KB embed table + 2x32 KB B
// double-buffer = 72 KB -> 2 independent blocks/CU (decoupled barriers).
// A-frags are gathered DIRECTLY into registers from the table (2 ds_read_b64
// per row-tile) -- no A staging, no A frag reads. 32 MFMAs per 8 B-frag
// reads: 2x the FLOP/LDS-byte of the 64x64 geometry.
// vmcnt discipline: DMAs for half-step s are ALWAYS issued before any newer
// x-loads (prologue order matters: queue [DMA x8, x x4] so VMWAIT(4) drains
// exactly the DMAs -- m135 in-order queue semantics).
__global__ __launch_bounds__(256, 2) void fused_gemm_kernel(
    const int* __restrict__ x,
    const float* __restrict__ We,
    const float* __restrict__ be,
    const uint16_t* __restrict__ Btf,
    const float* __restrict__ bias,
    float* __restrict__ C) {
  __shared__ __align__(16) uint16_t web[NCLS * 4];   // 8 KB: bf16(We[c][e]+be[e])
  __shared__ __align__(16) uint16_t Bs[2 * 16384];   // 64 KB: 2 half-buffers

  const int tid = threadIdx.x;
  const int bm  = blockIdx.x;            // 0..255 (64-row band)
  const int bn  = blockIdx.y;            // 0..1   (512-col band)
  const int w   = tid >> 6;              // wave = wc, 0..3 (128-col sub-band)
  const int l   = tid & 63;
  const int lm  = l & 15;
  const int q4  = l >> 4;

  const int row0 = bm * 64;
  const int col0 = bn * 512;

  // ---- embed table -> LDS (bias folded, bf16) ----
  {
    const float4 bb = *(const float4*)be;
    #pragma unroll
    for (int c0 = 0; c0 < NCLS; c0 += 256) {
      const int c = c0 + tid;
      const float4 wv = *(const float4*)(We + (size_t)c * 4);
      bf16x4 t;
      t[0] = (short)f2bf(wv.x + bb.x);
      t[1] = (short)f2bf(wv.y + bb.y);
      t[2] = (short)f2bf(wv.z + bb.z);
      t[3] = (short)f2bf(wv.w + bb.w);
      *(bf16x4*)(web + (size_t)c * 4) = t;
    }
  }
  __syncthreads();                       // table visible to all waves

  // ---- per-lane pointers ----
  // A: row-tile i -> row row0 + i*16 + lm, class pair at pos s*8 + q4*2.
  const int* xr0 = x + (size_t)(row0 +  0 + lm) * NP + q4 * 2;
  const int* xr1 = x + (size_t)(row0 + 16 + lm) * NP + q4 * 2;
  const int* xr2 = x + (size_t)(row0 + 32 + lm) * NP + q4 * 2;
  const int* xr3 = x + (size_t)(row0 + 48 + lm) * NP + q4 * 2;
  const uint16_t* const btb = Btf + (size_t)bn * (NH * 16384);

  f32x4 acc[4][8];
  #pragma unroll
  for (int i = 0; i < 4; i++)
    #pragma unroll
    for (int j = 0; j < 8; j++)
      acc[i][j] = (f32x4){0.f, 0.f, 0.f, 0.f};

  // ---- prologue: stage(0) FIRST, then x(0) (queue order: DMA x8, x x4) ----
  #pragma unroll
  for (int r = 0; r < 8; ++r)
    GLOAD_LDS16(btb + (size_t)(r * 256 + tid) * 8, Bs + (size_t)(r * 256 + tid) * 8);
  MEMFENCE();
  int2 xq[4], xn[4];
  xq[0] = *(const int2*)xr0;
  xq[1] = *(const int2*)xr1;
  xq[2] = *(const int2*)xr2;
  xq[3] = *(const int2*)xr3;

  for (int s = 0; s < NH; ++s) {
    const int cb = s & 1;
    // drain DMA(s); up to 4 newer x-loads may stay in flight
    VMWAIT(4);
    MEMFENCE();
    __builtin_amdgcn_s_barrier();
    MEMFENCE();

    // stage s+1 into the other buffer (overlaps compute(s)); DMAs before x
    if (s + 1 < NH) {
      const uint16_t* bsrc = btb + (size_t)(s + 1) * 16384;
      uint16_t* bdst = Bs + (size_t)(cb ^ 1) * 16384;
      #pragma unroll
      for (int r = 0; r < 8; ++r)
        GLOAD_LDS16(bsrc + (size_t)(r * 256 + tid) * 8, bdst + (size_t)(r * 256 + tid) * 8);
      MEMFENCE();
      // x prefetch for s+1 (register-destined; compiler waits before gathers)
      xn[0] = *(const int2*)(xr0 + (s + 1) * 8);
      xn[1] = *(const int2*)(xr1 + (s + 1) * 8);
      xn[2] = *(const int2*)(xr2 + (s + 1) * 8);
      xn[3] = *(const int2*)(xr3 + (s + 1) * 8);
    }

    // ---- compute(s): 8 B-frag reads + 8 A-gathers -> 32 MFMAs ----
    const uint16_t* bb_ = Bs + (size_t)cb * 16384;
    bf16x8 bfr[8];
    #pragma unroll
    for (int j = 0; j < 8; j++)
      bfr[j] = *(const bf16x8*)(bb_ + (size_t)((w * 8 + j) * 64 + l) * 8);

    bf16x8 af[4];
    #pragma unroll
    for (int i = 0; i < 4; i++) {
      union { bf16x8 v; struct { bf16x4 lo, hi; } s_; } u;
      u.s_.lo = *(const bf16x4*)(web + ((unsigned)xq[i].x * 4u));
      u.s_.hi = *(const bf16x4*)(web + ((unsigned)xq[i].y * 4u));
      af[i] = u.v;
    }

    __builtin_amdgcn_s_setprio(1);
    #pragma unroll
    for (int i = 0; i < 4; i++)
      #pragma unroll
      for (int j = 0; j < 8; j++)
        acc[i][j] = __builtin_amdgcn_mfma_f32_16x16x32_bf16(af[i], bfr[j], acc[i][j], 0, 0, 0);
    __builtin_amdgcn_s_setprio(0);

    if (s + 1 < NH) {
      #pragma unroll
      for (int i = 0; i < 4; i++) xq[i] = xn[i];
    }
  }

  // ---- epilogue: D[row = q4*4 + r][col = lm] per 16x16 frag (m89/m91-verified) ----
  float bvals[8];
  #pragma unroll
  for (int j = 0; j < 8; j++)
    bvals[j] = bias[col0 + w * 128 + j * 16 + lm];

  #pragma unroll
  for (int i = 0; i < 4; i++) {
    const int rbase = row0 + i * 16 + q4 * 4;
    #pragma unroll
    for (int j = 0; j < 8; j++) {
      const int col = col0 + w * 128 + j * 16 + lm;
      #pragma unroll
      for (int r = 0; r < 4; r++)
        C[(size_t)(rbase + r) * NDIM + col] = acc[i][j][r] + bvals[j];
    }
  }
}

// ---------------- fallback (workspace too small): fp32 naive ----------------
__global__ void naive_kernel(const int* __restrict__ x,
                             const float* __restrict__ We,
                             const float* __restrict__ be,
                             const float* __restrict__ Wd,
                             const float* __restrict__ bd,
                             float* __restrict__ out) {
  __shared__ float emb[KDIM];
  const int b = blockIdx.x;
  const int tid = threadIdx.x;
  {
    const int cls = x[(size_t)b * NP + tid];
    const float4 e  = *(const float4*)(We + (size_t)cls * 4);
    const float4 bb = *(const float4*)be;
    emb[tid * 4 + 0] = e.x + bb.x;
    emb[tid * 4 + 1] = e.y + bb.y;
    emb[tid * 4 + 2] = e.z + bb.z;
    emb[tid * 4 + 3] = e.w + bb.w;
  }
  __syncthreads();
  float acc0 = bd[tid], acc1 = bd[tid + 256], acc2 = bd[tid + 512], acc3 = bd[tid + 768];
  for (int k = 0; k < KDIM; ++k) {
    const float a = emb[k];
    const float* wv = Wd + (size_t)k * NDIM + tid;
    acc0 += a * wv[0];
    acc1 += a * wv[256];
    acc2 += a * wv[512];
    acc3 += a * wv[768];
  }
  float* o = out + (size_t)b * NDIM + tid;
  o[0] = acc0; o[256] = acc1; o[512] = acc2; o[768] = acc3;
}

// ---------------- launch ----------------
extern "C" void kernel_launch(void* const* d_in, const int* in_sizes, int n_in,
                              void* d_out, int out_size, void* d_ws, size_t ws_size,
                              hipStream_t stream) {
  const int*   x  = (const int*)d_in[0];
  const float* We = (const float*)d_in[1];
  const float* be = (const float*)d_in[2];
  const float* Wd = (const float*)d_in[3];
  const float* bd = (const float*)d_in[4];
  float* out = (float*)d_out;

  const size_t needB = (size_t)NDIM * KDIM * sizeof(uint16_t);  // 2 MB

  if (ws_size >= needB) {
    uint16_t* Btw = (uint16_t*)d_ws;
    build_bt_kernel<<<dim3(NDIM / 32, KDIM / 32), dim3(32, 8), 0, stream>>>(Wd, Btw);
    fused_gemm_kernel<<<dim3(MB / 64, NDIM / 512), 256, 0, stream>>>(x, We, be, Btw, bd, out);
  } else {
    naive_kernel<<<MB, 256, 0, stream>>>(x, We, be, Wd, bd, out);
  }
}